// Round 5
// baseline (138.975 us; speedup 1.0000x reference)
//
#include <hip/hip_runtime.h>
#include <hip/hip_bf16.h>
#include <hip/hip_cooperative_groups.h>

namespace cg = cooperative_groups;

#define BATCH 8
#define SEQ   4096
#define NST   512     // state dim == GEMM K
#define DM    512     // d_model  == GEMM N
#define NCHUNK 32
#define TCH    128    // SEQ / NCHUNK
#define LDP    (NST + 8)   // LDS row pitch in shorts

typedef __attribute__((ext_vector_type(4))) float f32x4;
typedef __attribute__((ext_vector_type(2))) float f32x2;
typedef __attribute__((ext_vector_type(8))) short short8v;   // 8 bf16
typedef __attribute__((ext_vector_type(4))) short short4v;

__device__ __forceinline__ short f2bf(float f) {
  union { float f; unsigned u; } v; v.f = f;
  unsigned r = v.u + 0x7FFFu + ((v.u >> 16) & 1u);   // RNE truncate to bf16
  return (short)(r >> 16);
}

// ============================ MEGA (cooperative) ============================
// One kernel: transQ (blocks 0-63) -> local scan (x_local in regs) -> grid.sync
// -> per-block prefix from S -> correction -> LDS X -> single-pass GEMM -> y.
__global__ __launch_bounds__(512) void k_mega(
    const float* __restrict__ u, const float* __restrict__ Lam,
    const float* __restrict__ Bv, const float* __restrict__ log_dt,
    const float* __restrict__ Q, float* __restrict__ S,
    short* __restrict__ Qt, float* __restrict__ y) {
  __shared__ __align__(16) short X[TCH][LDP];     // 133120 B -> 1 block/CU
  const int tid = threadIdx.x;
  const int b = blockIdx.x & (BATCH - 1);
  const int c = blockIdx.x >> 3;

  // ---- phase 0: transQ, blocks 0..63 (c = 0..7, the ones with least phase-2 work)
  if (blockIdx.x < 64) {
    short (*tile)[68] = (short(*)[68])&X[0][0];
    const int bn = (blockIdx.x & 7) * 64;
    const int bd = (blockIdx.x >> 3) * 64;
    const int tc4 = (tid & 15) * 4;
    const int tr = tid >> 4;                      // 0..31
    #pragma unroll
    for (int i = 0; i < 2; ++i) {
      int r = tr + i * 32;                        // n-local
      f32x4 v = *(const f32x4*)(Q + (size_t)(bn + r) * DM + bd + tc4);
      short4v h;
      h[0] = f2bf(v[0]); h[1] = f2bf(v[1]); h[2] = f2bf(v[2]); h[3] = f2bf(v[3]);
      *(short4v*)&tile[r][tc4] = h;
    }
    __syncthreads();
    #pragma unroll
    for (int i = 0; i < 2; ++i) {
      int r = tr + i * 32;                        // d-local
      short4v h;
      #pragma unroll
      for (int j = 0; j < 4; ++j) h[j] = tile[tc4 + j][r];
      *(short4v*)(Qt + (size_t)(bd + r) * NST + bn + tc4) = h;
    }
    __syncthreads();                              // X free again
  }

  // ---- phase 1: local scan (x starts at 0), x_local kept in registers
  const float dt = expf(log_dt[0]);
  const float a  = expf(-dt * expf(Lam[tid]));
  const float g  = dt * Bv[tid];
  const float* up = u + ((size_t)b * SEQ + (size_t)c * TCH) * NST + tid;
  float xl[TCH];
  {
    float x = 0.f;
    for (int t0 = 0; t0 < TCH; t0 += 32) {
      float ur[32];
      #pragma unroll
      for (int j = 0; j < 32; ++j) ur[j] = up[(size_t)(t0 + j) * NST];
      #pragma unroll
      for (int j = 0; j < 32; ++j) { x = fmaf(a, x, g * ur[j]); xl[t0 + j] = x; }
    }
    S[(c * BATCH + b) * NST + tid] = x;           // chunk sum
  }
  __threadfence();
  cg::this_grid().sync();

  // ---- phase 2: incoming state for this chunk from all S[c'<c]
  float aT = a;
  #pragma unroll
  for (int i = 0; i < 7; ++i) aT *= aT;           // a^128
  float xin = 0.f;
  {
    int cp = 0;
    for (; cp + 8 <= c; cp += 8) {
      float sb[8];
      #pragma unroll
      for (int j = 0; j < 8; ++j) sb[j] = S[((cp + j) * BATCH + b) * NST + tid];
      #pragma unroll
      for (int j = 0; j < 8; ++j) xin = fmaf(aT, xin, sb[j]);
    }
    for (; cp < c; ++cp) xin = fmaf(aT, xin, S[(cp * BATCH + b) * NST + tid]);
  }

  // ---- phase 3: correction x[t] = xl[t] + a^{t+1}*xin -> bf16 -> LDS
  {
    float ap = a;
    #pragma unroll
    for (int t = 0; t < TCH; ++t) {
      X[t][tid] = f2bf(fmaf(ap, xin, xl[t]));
      ap *= a;
    }
  }
  __syncthreads();

  // ---- phase 4: GEMM 128x512x512, single pass, wave wc owns 64 cols x 128 rows
  const int lane = tid & 63;
  const int wc   = tid >> 6;                      // 0..7
  const int l15  = lane & 15;
  const int lhi  = lane >> 4;
  const int ka   = lhi * 8;
  const short* qbase = Qt + (size_t)(wc * 64 + l15) * NST + ka;
  float* yb = y + ((size_t)b * SEQ + (size_t)c * TCH) * DM;

  f32x4 acc[8][4];
  #pragma unroll
  for (int mi = 0; mi < 8; ++mi)
    #pragma unroll
    for (int nf = 0; nf < 4; ++nf) acc[mi][nf] = (f32x4){0.f, 0.f, 0.f, 0.f};

  for (int kk = 0; kk < 16; ++kk) {
    const int k0 = kk * 32;
    short8v bfrag[4];
    #pragma unroll
    for (int nf = 0; nf < 4; ++nf)
      bfrag[nf] = *(const short8v*)(qbase + (size_t)nf * 16 * NST + k0);
    short8v afrag[8];
    #pragma unroll
    for (int mi = 0; mi < 8; ++mi)
      afrag[mi] = *(const short8v*)&X[mi * 16 + l15][k0 + ka];
    #pragma unroll
    for (int mi = 0; mi < 8; ++mi)
      #pragma unroll
      for (int nf = 0; nf < 4; ++nf)
        acc[mi][nf] = __builtin_amdgcn_mfma_f32_16x16x32_bf16(afrag[mi], bfrag[nf], acc[mi][nf], 0, 0, 0);
  }

  // ---- y stores: each (i,lhi) group = 16 lanes x 4B = full 64B lines
  #pragma unroll
  for (int mi = 0; mi < 8; ++mi)
    #pragma unroll
    for (int nf = 0; nf < 4; ++nf) {
      const int rr = mi * 16 + lhi * 4;
      const int cc = wc * 64 + nf * 16 + l15;
      #pragma unroll
      for (int i = 0; i < 4; ++i)
        yb[(size_t)(rr + i) * DM + cc] = acc[mi][nf][i];
    }
}

// ============================ FALLBACK (round-4 path) ============================
__global__ void k_scan_sums(const float* __restrict__ u, const float* __restrict__ Lam,
                            const float* __restrict__ Bv, const float* __restrict__ log_dt,
                            float* __restrict__ S) {
  int gid = blockIdx.x * 256 + threadIdx.x;
  int n2 = (gid & 255) * 2;
  int bc = gid >> 8;
  int b  = bc & (BATCH - 1);
  int c  = bc >> 3;
  float dt = expf(log_dt[0]);
  f32x2 lam = *(const f32x2*)(Lam + n2);
  f32x2 bv  = *(const f32x2*)(Bv + n2);
  float a0 = expf(-dt * expf(lam[0])), a1 = expf(-dt * expf(lam[1]));
  float g0 = dt * bv[0],               g1 = dt * bv[1];
  const float* up = u + ((size_t)b * SEQ + (size_t)c * TCH) * NST + n2;
  float s0 = 0.f, s1 = 0.f;
  #pragma unroll 8
  for (int t = 0; t < TCH; ++t) {
    f32x2 v = *(const f32x2*)(up + (size_t)t * NST);
    s0 = fmaf(a0, s0, g0 * v[0]);
    s1 = fmaf(a1, s1, g1 * v[1]);
  }
  *(f32x2*)(S + (c * BATCH + b) * NST + n2) = (f32x2){s0, s1};
}

__global__ void k_propagate(const float* __restrict__ Lam, const float* __restrict__ log_dt,
                            const float* __restrict__ S, float* __restrict__ Xc) {
  int gid = blockIdx.x * 256 + threadIdx.x;
  int n = gid & (NST - 1);
  int b = gid >> 9;
  float dt = expf(log_dt[0]);
  float a  = expf(-dt * expf(Lam[n]));
  float aT = a;
  #pragma unroll
  for (int i = 0; i < 7; ++i) aT *= aT;
  float x = 0.f;
  for (int c = 0; c < NCHUNK; ++c) {
    Xc[(c * BATCH + b) * NST + n] = x;
    x = fmaf(aT, x, S[(c * BATCH + b) * NST + n]);
  }
}

__global__ void k_transQ(const float* __restrict__ Q, short* __restrict__ Qt) {
  __shared__ short tile[64][68];
  int bn = (blockIdx.x & 7) * 64;
  int bd = (blockIdx.x >> 3) * 64;
  int tc = threadIdx.x & 15;
  int tr = threadIdx.x >> 4;
  #pragma unroll
  for (int i = 0; i < 4; ++i) {
    int r = tr + i * 16;
    f32x4 v = *(const f32x4*)(Q + (size_t)(bn + r) * DM + bd + tc * 4);
    short4v h;
    h[0] = f2bf(v[0]); h[1] = f2bf(v[1]); h[2] = f2bf(v[2]); h[3] = f2bf(v[3]);
    *(short4v*)&tile[r][tc * 4] = h;
  }
  __syncthreads();
  #pragma unroll
  for (int i = 0; i < 4; ++i) {
    int r = tr + i * 16;
    short4v h;
    #pragma unroll
    for (int j = 0; j < 4; ++j) h[j] = tile[tc * 4 + j][r];
    *(short4v*)(Qt + (size_t)(bd + r) * NST + bn + tc * 4) = h;
  }
}

__global__ __launch_bounds__(512) void k_fused(
    const float* __restrict__ u, const float* __restrict__ Lam,
    const float* __restrict__ Bv, const float* __restrict__ log_dt,
    const float* __restrict__ Xc, const short* __restrict__ Qt,
    float* __restrict__ y) {
  __shared__ __align__(16) short X[2][64][LDP];
  const int tid = threadIdx.x;
  const int b = blockIdx.x & (BATCH - 1);
  const int c = blockIdx.x >> 3;
  const float dt = expf(log_dt[0]);
  const float a  = expf(-dt * expf(Lam[tid]));
  const float g  = dt * Bv[tid];
  float x = Xc[(c * BATCH + b) * NST + tid];
  const float* up = u + ((size_t)b * SEQ + (size_t)c * TCH) * NST + tid;
  {
    float ur[64];
    #pragma unroll
    for (int t = 0; t < 64; ++t) ur[t] = up[(size_t)t * NST];
    #pragma unroll
    for (int t = 0; t < 64; ++t) { x = fmaf(a, x, g * ur[t]); X[0][t][tid] = f2bf(x); }
  }
  __syncthreads();
  const int lane = tid & 63;
  const int wc   = tid >> 6;
  const int l15  = lane & 15;
  const int lhi  = lane >> 4;
  const int ka   = lhi * 8;
  const short* qbase = Qt + (size_t)(wc * 64 + l15) * NST + ka;
  float* yb = y + ((size_t)b * SEQ + (size_t)c * TCH) * DM;
  float ur2[64];
  f32x4 acc[4][4];
  #pragma unroll
  for (int mi = 0; mi < 4; ++mi)
    #pragma unroll
    for (int nf = 0; nf < 4; ++nf) acc[mi][nf] = (f32x4){0.f, 0.f, 0.f, 0.f};
  #pragma unroll
  for (int kk = 0; kk < 16; ++kk) {
    const int k0 = kk * 32;
    #pragma unroll
    for (int j = 0; j < 4; ++j) ur2[kk * 4 + j] = up[(size_t)(64 + kk * 4 + j) * NST];
    short8v afrag[4];
    #pragma unroll
    for (int mi = 0; mi < 4; ++mi) afrag[mi] = *(const short8v*)&X[0][mi * 16 + l15][k0 + ka];
    short8v bfrag[4];
    #pragma unroll
    for (int nf = 0; nf < 4; ++nf) bfrag[nf] = *(const short8v*)(qbase + (size_t)nf * 16 * NST + k0);
    #pragma unroll
    for (int mi = 0; mi < 4; ++mi)
      #pragma unroll
      for (int nf = 0; nf < 4; ++nf)
        acc[mi][nf] = __builtin_amdgcn_mfma_f32_16x16x32_bf16(afrag[mi], bfrag[nf], acc[mi][nf], 0, 0, 0);
  }
  #pragma unroll
  for (int mi = 0; mi < 4; ++mi)
    #pragma unroll
    for (int nf = 0; nf < 4; ++nf) {
      const int rr = mi * 16 + lhi * 4;
      const int cc = wc * 64 + nf * 16 + l15;
      #pragma unroll
      for (int i = 0; i < 4; ++i) yb[(size_t)(rr + i) * DM + cc] = acc[mi][nf][i];
    }
  #pragma unroll
  for (int t = 0; t < 64; ++t) { x = fmaf(a, x, g * ur2[t]); X[1][t][tid] = f2bf(x); }
  __syncthreads();
  #pragma unroll
  for (int mi = 0; mi < 4; ++mi)
    #pragma unroll
    for (int nf = 0; nf < 4; ++nf) acc[mi][nf] = (f32x4){0.f, 0.f, 0.f, 0.f};
  #pragma unroll
  for (int kk = 0; kk < 16; ++kk) {
    const int k0 = kk * 32;
    short8v afrag[4];
    #pragma unroll
    for (int mi = 0; mi < 4; ++mi) afrag[mi] = *(const short8v*)&X[1][mi * 16 + l15][k0 + ka];
    short8v bfrag[4];
    #pragma unroll
    for (int nf = 0; nf < 4; ++nf) bfrag[nf] = *(const short8v*)(qbase + (size_t)nf * 16 * NST + k0);
    #pragma unroll
    for (int mi = 0; mi < 4; ++mi)
      #pragma unroll
      for (int nf = 0; nf < 4; ++nf)
        acc[mi][nf] = __builtin_amdgcn_mfma_f32_16x16x32_bf16(afrag[mi], bfrag[nf], acc[mi][nf], 0, 0, 0);
  }
  #pragma unroll
  for (int mi = 0; mi < 4; ++mi)
    #pragma unroll
    for (int nf = 0; nf < 4; ++nf) {
      const int rr = 64 + mi * 16 + lhi * 4;
      const int cc = wc * 64 + nf * 16 + l15;
      #pragma unroll
      for (int i = 0; i < 4; ++i) yb[(size_t)(rr + i) * DM + cc] = acc[mi][nf][i];
    }
}

extern "C" void kernel_launch(void* const* d_in, const int* in_sizes, int n_in,
                              void* d_out, int out_size, void* d_ws, size_t ws_size,
                              hipStream_t stream) {
  const float* u      = (const float*)d_in[0];
  const float* Lam    = (const float*)d_in[1];
  const float* Bv     = (const float*)d_in[2];
  const float* Q      = (const float*)d_in[3];
  const float* log_dt = (const float*)d_in[4];
  float* out = (float*)d_out;

  float* S  = (float*)d_ws;                                  // 512 KB
  float* Xc = S + NCHUNK * BATCH * NST;                      // 512 KB (fallback only)
  short* Qt = (short*)(Xc + NCHUNK * BATCH * NST);           // 512 KB bf16

  void* args[] = {(void*)&u, (void*)&Lam, (void*)&Bv, (void*)&log_dt,
                  (void*)&Q, (void*)&S, (void*)&Qt, (void*)&out};
  hipError_t e = hipLaunchCooperativeKernel((const void*)k_mega,
                                            dim3(NCHUNK * BATCH), dim3(512),
                                            args, 0, stream);
  if (e != hipSuccess) {
    // fallback: proven round-4 four-kernel path (identical output)
    hipLaunchKernelGGL(k_scan_sums, dim3(NCHUNK * BATCH), dim3(256), 0, stream,
                       u, Lam, Bv, log_dt, S);
    hipLaunchKernelGGL(k_propagate, dim3(BATCH * NST / 256), dim3(256), 0, stream,
                       Lam, log_dt, S, Xc);
    hipLaunchKernelGGL(k_transQ, dim3(64), dim3(256), 0, stream, Q, Qt);
    hipLaunchKernelGGL(k_fused, dim3(NCHUNK * BATCH), dim3(512), 0, stream,
                       u, Lam, Bv, log_dt, Xc, Qt, out);
  }
}